// Round 7
// baseline (402.785 us; speedup 1.0000x reference)
//
#include <hip/hip_runtime.h>
#include <math.h>

#define LOG_SQRT_2PI 0.9189385332046727f   // 0.5*ln(2*pi)

typedef float f32x4 __attribute__((ext_vector_type(4)));

// ---------------------------------------------------------------------------
// Reduction duty (log_prior, log_variational_posterior over S*J elements).
// ws layout: ws[0]=log_prior (double), ws[1]=log_var_post (double),
//            bytes [16,20) = uint completion counter. Zeroed by memset.
// ---------------------------------------------------------------------------
__device__ __forceinline__
void reduce_duty(const float* __restrict__ mu,
                 const float* __restrict__ rho,
                 const float* __restrict__ eps,
                 float* __restrict__ out_scalars,
                 double* __restrict__ ws,
                 int S, int J, int nRed)
{
    const int n = S * J;
    double lvp = 0.0, lpr = 0.0;
    const float log_half   = -0.6931471805599453f;   // ln(0.5)
    const float log_sigma2 = -6.214608098422191f;    // ln(0.002)
    const float inv_2s2_2  = 125000.0f;              // 1/(2*0.002^2)

    for (int idx = blockIdx.x * blockDim.x + threadIdx.x; idx < n;
         idx += nRed * blockDim.x) {
        const int j = idx % J;
        const float m = mu[j];
        const float r = rho[j];
        const float e = eps[idx];
        const float sg = log1pf(expf(r));        // softplus
        const float w  = m + sg * e;

        const float d = w - m;                    // = sg*e
        lvp += (double)(-LOG_SQRT_2PI - logf(sg) - (d * d) / (2.0f * sg * sg));

        const float w2  = w * w;
        const float lp1 = -LOG_SQRT_2PI - 0.5f * w2 + log_half;
        const float lp2 = -LOG_SQRT_2PI - log_sigma2 - w2 * inv_2s2_2 + log_half;
        const float mx  = fmaxf(lp1, lp2);
        const float mn  = fminf(lp1, lp2);
        lpr += (double)(mx + log1pf(expf(mn - mx)));
    }

    for (int off = 32; off > 0; off >>= 1) {
        lvp += __shfl_down(lvp, off, 64);
        lpr += __shfl_down(lpr, off, 64);
    }
    __shared__ double s_l[2][4];
    const int wid = threadIdx.x >> 6, lane = threadIdx.x & 63;
    if (lane == 0) { s_l[0][wid] = lvp; s_l[1][wid] = lpr; }
    __syncthreads();
    if (threadIdx.x == 0) {
        const int nw = blockDim.x >> 6;
        double bl_lvp = 0.0, bl_lpr = 0.0;
        for (int i = 0; i < nw; ++i) { bl_lvp += s_l[0][i]; bl_lpr += s_l[1][i]; }
        atomicAdd(&ws[0], bl_lpr);
        atomicAdd(&ws[1], bl_lvp);
        __threadfence();
        unsigned int* counter = (unsigned int*)(ws + 2);
        const unsigned int prev = atomicAdd(counter, 1u);
        if (prev == (unsigned)(nRed - 1)) {
            __threadfence();
            out_scalars[0] = (float)atomicAdd(&ws[0], 0.0);  // log_prior
            out_scalars[1] = (float)atomicAdd(&ws[1], 0.0);  // log_var_post
        }
    }
}

// ---------------------------------------------------------------------------
// OLD fused kernel (round-5, unchanged): needed so dur_us arithmetic
// (overhead + T_old = 335us) lets us solve T_new = dur_us - 335.
// ---------------------------------------------------------------------------
__global__ __launch_bounds__(256)
void bel_fused4(const f32x4* __restrict__ x4,
                const float* __restrict__ mu,
                const float* __restrict__ rho,
                const float* __restrict__ eps,
                f32x4* __restrict__ o4,
                float* __restrict__ out_scalars,
                double* __restrict__ ws,
                int B, int J, int jblocks, int bstride, int nRed)
{
    if ((int)blockIdx.x < nRed)
        reduce_duty(mu, rho, eps, out_scalars, ws, 4, J, nRed);

    const int Jv  = J >> 2;
    const int TW  = blockDim.x * 2;
    const int jb  = blockIdx.x % jblocks;
    const int bstart = blockIdx.x / jblocks;
    const int jv0 = jb * TW + threadIdx.x;
    const int jv1 = jv0 + blockDim.x;

    const f32x4* muv  = (const f32x4*)mu;
    const f32x4* rhov = (const f32x4*)rho;
    const f32x4* ev   = (const f32x4*)eps;

    f32x4 w[2][4];
    #pragma unroll
    for (int c = 0; c < 2; ++c) {
        const int jv = c ? jv1 : jv0;
        const f32x4 m = muv[jv];
        const f32x4 r = rhov[jv];
        f32x4 sg;
        sg.x = log1pf(expf(r.x)); sg.y = log1pf(expf(r.y));
        sg.z = log1pf(expf(r.z)); sg.w = log1pf(expf(r.w));
        #pragma unroll
        for (int s = 0; s < 4; ++s)
            w[c][s] = m + sg * ev[s * Jv + jv];
    }

    const size_t plane = (size_t)B * Jv;

    #pragma unroll 4
    for (int b = bstart; b < B; b += bstride) {
        const size_t r0 = (size_t)b * Jv + jv0;
        const size_t r1 = (size_t)b * Jv + jv1;
        const f32x4 x0 = x4[r0];
        const f32x4 x1 = x4[r1];
        o4[0 * plane + r0] = x0 * w[0][0];
        o4[0 * plane + r1] = x1 * w[1][0];
        o4[1 * plane + r0] = x0 * w[0][1];
        o4[1 * plane + r1] = x1 * w[1][1];
        o4[2 * plane + r0] = x0 * w[0][2];
        o4[2 * plane + r1] = x1 * w[1][2];
        o4[3 * plane + r0] = x0 * w[0][3];
        o4[3 * plane + r1] = x1 * w[1][3];
    }
}

// ---------------------------------------------------------------------------
// NEW candidate: stream-only, bit-identical output values (overwrites out).
// One block = 4 consecutive rows, full row coverage (4 chunks x 256 thr).
// Per row each of the 5 HBM streams gets a contiguous 16KB burst; consecutive
// rows extend each stream sequentially (64KB runs/block). NT loads keep the
// x read stream out of L2.
// ---------------------------------------------------------------------------
__global__ __launch_bounds__(256)
void bel_stream4(const f32x4* __restrict__ x4,
                 const float* __restrict__ mu,
                 const float* __restrict__ rho,
                 const float* __restrict__ eps,
                 f32x4* __restrict__ o4,
                 int B, int Jv, int rowsPerBlock)
{
    const int tid = threadIdx.x;
    const int bs  = blockDim.x;              // 256
    const size_t plane = (size_t)B * Jv;

    // per-thread weights: 4 column-groups x 4 samples (bit-identical math
    // to bel_fused4: w = mu + log1p(exp(rho)) * eps, out = x * w)
    f32x4 w[4][4];
    #pragma unroll
    for (int c = 0; c < 4; ++c) {
        const int jv = c * bs + tid;
        const f32x4 m = ((const f32x4*)mu)[jv];
        const f32x4 r = ((const f32x4*)rho)[jv];
        f32x4 sg;
        sg.x = log1pf(expf(r.x)); sg.y = log1pf(expf(r.y));
        sg.z = log1pf(expf(r.z)); sg.w = log1pf(expf(r.w));
        #pragma unroll
        for (int s = 0; s < 4; ++s)
            w[c][s] = m + sg * ((const f32x4*)eps)[s * Jv + jv];
    }

    const int r0 = blockIdx.x * rowsPerBlock;
    for (int r = r0; r < r0 + rowsPerBlock; ++r) {
        const size_t rb = (size_t)r * Jv + tid;
        f32x4 xv[4];
        #pragma unroll
        for (int c = 0; c < 4; ++c)
            xv[c] = __builtin_nontemporal_load(&x4[rb + (size_t)c * bs]);
        #pragma unroll
        for (int s = 0; s < 4; ++s) {
            #pragma unroll
            for (int c = 0; c < 4; ++c)
                o4[s * plane + rb + (size_t)c * bs] = xv[c] * w[c][s];
        }
    }
}

// ---------------------------------------------------------------------------
// Generic fallbacks (S != 4 or odd shapes).
// ---------------------------------------------------------------------------
__global__ __launch_bounds__(256)
void bel_reduce_gen(const float* __restrict__ mu, const float* __restrict__ rho,
                    const float* __restrict__ eps, float* __restrict__ out_scalars,
                    double* __restrict__ ws, int S, int J, int nRed)
{
    reduce_duty(mu, rho, eps, out_scalars, ws, S, J, nRed);
}

__global__ __launch_bounds__(256)
void bel_scale_gen(const f32x4* __restrict__ x4,
                   const float* __restrict__ mu, const float* __restrict__ rho,
                   const float* __restrict__ eps, f32x4* __restrict__ o4,
                   long long total4, int Jv, int B, int S)
{
    long long idx = (long long)blockIdx.x * blockDim.x + threadIdx.x;
    const long long stride = (long long)gridDim.x * blockDim.x;
    const long long plane = (long long)B * Jv;
    for (; idx < (long long)S * plane; idx += stride) {
        const int s  = (int)(idx / plane);
        const long long r = idx % plane;
        const int jv = (int)(r % Jv);
        const f32x4 muv  = ((const f32x4*)mu)[jv];
        const f32x4 rhov = ((const f32x4*)rho)[jv];
        const f32x4 evv  = ((const f32x4*)eps)[(long long)s * Jv + jv];
        const f32x4 xv   = x4[r];
        f32x4 sg;
        sg.x = log1pf(expf(rhov.x)); sg.y = log1pf(expf(rhov.y));
        sg.z = log1pf(expf(rhov.z)); sg.w = log1pf(expf(rhov.w));
        o4[idx] = xv * (muv + sg * evv);
    }
}

extern "C" void kernel_launch(void* const* d_in, const int* in_sizes, int n_in,
                              void* d_out, int out_size, void* d_ws, size_t ws_size,
                              hipStream_t stream) {
    const float* x   = (const float*)d_in[0];
    const float* mu  = (const float*)d_in[1];
    const float* rho = (const float*)d_in[2];
    const float* eps = (const float*)d_in[3];

    const int J = in_sizes[1];
    const int B = in_sizes[0] / J;
    const int S = in_sizes[3] / J;

    float* out = (float*)d_out;
    float* out_scalars = out + (size_t)S * B * J;   // {log_prior, log_var_post}
    double* ws = (double*)d_ws;

    (void)hipMemsetAsync(d_ws, 0, 24, stream);

    const int nRed = 32;
    const int block = 256;
    const int Jv = J / 4;
    const int TW = block * 2;

    if (S == 4 && (Jv % (4 * block)) == 0 && (B % 4) == 0) {
        // 1) old fused kernel, unchanged config (reduction + full output)
        const int jblocks = Jv / TW;
        int bstride = 1024;
        if (bstride > B) bstride = B;
        const int grid = jblocks * bstride;
        bel_fused4<<<grid, block, 0, stream>>>(
            (const f32x4*)x, mu, rho, eps, (f32x4*)out, out_scalars, ws,
            B, J, jblocks, bstride, nRed);
        // 2) new candidate, overwrites out with identical values
        bel_stream4<<<B / 4, block, 0, stream>>>(
            (const f32x4*)x, mu, rho, eps, (f32x4*)out, B, Jv, 4);
    } else {
        bel_reduce_gen<<<nRed, block, 0, stream>>>(mu, rho, eps, out_scalars, ws, S, J, nRed);
        const long long total4 = (long long)S * B * Jv;
        long long blocks = (total4 + block - 1) / block;
        if (blocks > 2048) blocks = 2048;
        bel_scale_gen<<<(int)blocks, block, 0, stream>>>(
            (const f32x4*)x, mu, rho, eps, (f32x4*)out, total4, Jv, B, S);
    }
}